// Round 1
// baseline (6106.697 us; speedup 1.0000x reference)
//
#include <hip/hip_runtime.h>
#include <hip/hip_bf16.h>
#include <stdint.h>

#define TLEN   4096
#define BATCH  4
#define BT     (BATCH*TLEN)
#define MD     128
#define NHN    16
#define FF     512
#define MDNH   2048
#define LN100F 4.605170185988092f

typedef __attribute__((ext_vector_type(8))) short bf16x8;
typedef __attribute__((ext_vector_type(4))) float f32x4;

__device__ __forceinline__ float leakyf(float v){ return v >= 0.f ? v : 0.2f*v; }
__device__ __forceinline__ short f2bf(float v){ __hip_bfloat16 h = __float2bfloat16(v); return *reinterpret_cast<short*>(&h); }
__device__ __forceinline__ float rowsum16(float v){
  v += __shfl_xor(v,1); v += __shfl_xor(v,2); v += __shfl_xor(v,4); v += __shfl_xor(v,8);
  return v;
}

// ---------------------------------------------------------------------------
// K1: exact KNN (top-16 by squared Euclidean distance, ties -> lower index).
// 4 queries per block (1 per wave). Candidate coords staged in LDS.
// Key = (f32bits(d2) << 32) | idx  — unsigned compare == (d2 asc, idx asc).
// d2 computed with explicit non-fused mul/add to bit-match numpy fp32.
// ---------------------------------------------------------------------------
__global__ __launch_bounds__(256) void knn_kernel(const float* __restrict__ coords,
                                                  int* __restrict__ idx_out,
                                                  float* __restrict__ cs_out) {
  __shared__ float sc[TLEN*2];
  int blk = blockIdx.x;          // 4096 blocks
  int bb  = blk >> 10;           // 1024 blocks per batch
  int q0  = (blk & 1023) << 2;
  const float4* cb4 = (const float4*)(coords + (size_t)bb*TLEN*2);
  for (int i = threadIdx.x; i < TLEN*2/4; i += 256) ((float4*)sc)[i] = cb4[i];
  __syncthreads();

  int wid  = threadIdx.x >> 6;
  int lane = threadIdx.x & 63;
  int q    = q0 + wid;
  float qx = sc[q*2], qy = sc[q*2+1];

  unsigned long long top[16];
#pragma unroll
  for (int j = 0; j < 16; ++j) top[j] = ~0ull;

  for (int c = lane; c < TLEN; c += 64) {
    float dx = __fsub_rn(sc[c*2],   qx);
    float dy = __fsub_rn(sc[c*2+1], qy);
    float d2 = __fadd_rn(__fmul_rn(dx,dx), __fmul_rn(dy,dy));
    unsigned long long key = ((unsigned long long)__float_as_uint(d2) << 32) | (unsigned)c;
    if (key < top[15]) {
#pragma unroll
      for (int j = 15; j >= 1; --j)
        top[j] = (key < top[j-1]) ? top[j-1] : ((key < top[j]) ? key : top[j]);
      top[0] = (key < top[0]) ? key : top[0];
    }
  }

  // merge 64 sorted lists: 16 rounds of wave-min + winner pops its head
  unsigned long long myres = 0;
  for (int k = 0; k < 16; ++k) {
    unsigned long long m = top[0];
#pragma unroll
    for (int s = 1; s < 64; s <<= 1) {
      unsigned long long o = __shfl_xor(m, s);
      m = (o < m) ? o : m;
    }
    if (lane == k) myres = m;
    if (top[0] == m) {
#pragma unroll
      for (int j = 0; j < 15; ++j) top[j] = top[j+1];
      top[15] = ~0ull;
    }
  }
  if (lane < 16) {
    int ci = (int)(unsigned)(myres & 0xffffffffull);
    size_t o = ((size_t)(bb*TLEN + q))*16 + lane;
    idx_out[o] = ci;
    cs_out[o*2+0] = __fsub_rn(sc[ci*2],   qx);
    cs_out[o*2+1] = __fsub_rn(sc[ci*2+1], qy);
  }
}

// ---------------------------------------------------------------------------
// K0: fp32 [R][C] -> bf16 transposed [C][R] (for MFMA B-operand layout)
// ---------------------------------------------------------------------------
__global__ __launch_bounds__(256) void transpose_to_bf16(const float* __restrict__ in,
                                                         short* __restrict__ out,
                                                         int R, int C) {
  __shared__ float tile[32][33];
  int c0 = blockIdx.x*32, r0 = blockIdx.y*32;
  int tx = threadIdx.x & 31, ty = threadIdx.x >> 5;
  for (int i = ty; i < 32; i += 8) tile[i][tx] = in[(size_t)(r0+i)*C + c0+tx];
  __syncthreads();
  for (int i = ty; i < 32; i += 8) out[(size_t)(c0+i)*R + r0+tx] = f2bf(tile[tx][i]);
}

// ---------------------------------------------------------------------------
// K2 helper: [16,128] @ [128,128] with weight chunks staged through sW.
// thread (r = tid>>4, c0 = (tid&15)*8) computes out[r][c0..c0+7] into acc[8].
// ---------------------------------------------------------------------------
__device__ __forceinline__ void mm16x128(const float (*sIn)[132], const float* __restrict__ W,
                                         float* sW, float acc[8], int r, int c0, int tid) {
  for (int kc = 0; kc < 4; ++kc) {
    __syncthreads();
    const float4* wg = (const float4*)(W + kc*32*128);
    float4* sw4 = (float4*)sW;
#pragma unroll
    for (int i = 0; i < 4; ++i) sw4[tid + i*256] = wg[tid + i*256];
    __syncthreads();
#pragma unroll
    for (int kk = 0; kk < 32; ++kk) {
      float a = sIn[r][kc*32+kk];
      const float* wr_ = &sW[kk*128 + c0];
#pragma unroll
      for (int j = 0; j < 8; ++j) acc[j] = fmaf(a, wr_[j], acc[j]);
    }
  }
  __syncthreads();
}

// ---------------------------------------------------------------------------
// K2: full per-token pipeline. One 256-thread block per token.
//   gather -> pe MLP -> LN1 -> v,q,k -> cosine attention -> w_o -> LN2
//   -> mlp_nh -> +m -> LN3 over 2048 -> Hn (bf16)
// ---------------------------------------------------------------------------
__global__ __launch_bounds__(256,2) void token_kernel(
    const float* __restrict__ x, const int* __restrict__ idx, const float* __restrict__ cs,
    const float* __restrict__ w_v, const float* __restrict__ w_q, const float* __restrict__ w_k,
    const float* __restrict__ pe_w1, const float* __restrict__ pe_b1,
    const float* __restrict__ pe_w2, const float* __restrict__ pe_b2,
    const float* __restrict__ logit_scale,
    const float* __restrict__ w_o, const float* __restrict__ b_o,
    const float* __restrict__ nh_w1, const float* __restrict__ nh_b1,
    const float* __restrict__ nh_w2, const float* __restrict__ nh_b2,
    const float* __restrict__ ln1_g, const float* __restrict__ ln1_b,
    const float* __restrict__ ln2_g, const float* __restrict__ ln2_b,
    const float* __restrict__ ln3_g, const float* __restrict__ ln3_b,
    short* __restrict__ Hn) {
  __shared__ float sA[16][132];   // xg -> qn -> att_out
  __shared__ float sB[16][132];   // pe-hidden -> kn -> h2
  __shared__ float sV[16][132];
  __shared__ float sH1[16][132];
  __shared__ float sW[8192];      // weight staging (32KB)
  __shared__ float sAttn[4][16][16];
  __shared__ int   sIdx[16];
  __shared__ float sCs[16][2];
  __shared__ float sRed[8];
  __shared__ float sStats[2];

  int token = blockIdx.x;
  int bb    = token >> 12;           // /4096
  int tid   = threadIdx.x;
  int r  = tid >> 4;
  int cg = tid & 15;
  int c0 = cg << 3;

  if (tid < 16) sIdx[tid] = idx[(size_t)token*16 + tid];
  if (tid >= 32 && tid < 64) ((float*)sCs)[tid-32] = cs[(size_t)token*32 + (tid-32)];
  __syncthreads();

  // gather xg -> sA
  {
    const float4* xr = (const float4*)(x + (size_t)(bb*TLEN + sIdx[r])*MD);
    *(float4*)&sA[r][c0]   = xr[cg*2];
    *(float4*)&sA[r][c0+4] = xr[cg*2+1];
  }
  // pe hidden = leaky(cs @ pe_w1 + pe_b1) -> sB
  {
    float csx = sCs[r][0], csy = sCs[r][1];
#pragma unroll
    for (int j = 0; j < 8; ++j) {
      int c = c0 + j;
      sB[r][c] = leakyf(csx*pe_w1[c] + csy*pe_w1[128+c] + pe_b1[c]);
    }
  }

  // pe = hidden @ pe_w2 + pe_b2; s1 = xg + pe; LN1 -> sH1
  {
    float acc[8];
#pragma unroll
    for (int j = 0; j < 8; ++j) acc[j] = pe_b2[c0+j];
    mm16x128(sB, pe_w2, sW, acc, r, c0, tid);
    float s1[8], sum = 0.f, ssq = 0.f;
#pragma unroll
    for (int j = 0; j < 8; ++j) { s1[j] = sA[r][c0+j] + acc[j]; sum += s1[j]; ssq += s1[j]*s1[j]; }
    sum = rowsum16(sum); ssq = rowsum16(ssq);
    float mean = sum * (1.f/128.f);
    float var  = ssq * (1.f/128.f) - mean*mean;
    float rstd = rsqrtf(var + 1e-5f);
#pragma unroll
    for (int j = 0; j < 8; ++j)
      sH1[r][c0+j] = (s1[j]-mean)*rstd*ln1_g[c0+j] + ln1_b[c0+j];
  }

  // v = xg @ w_v -> sV
  {
    float acc[8] = {0,0,0,0,0,0,0,0};
    mm16x128(sA, w_v, sW, acc, r, c0, tid);
#pragma unroll
    for (int j = 0; j < 8; ++j) sV[r][c0+j] = acc[j];
  }

  // q = h1 @ w_q ; per-head L2-normalize -> qn in sA
  {
    float acc[8] = {0,0,0,0,0,0,0,0};
    mm16x128(sH1, w_q, sW, acc, r, c0, tid);
    float ssq = 0.f;
#pragma unroll
    for (int j = 0; j < 8; ++j) ssq += acc[j]*acc[j];
    ssq += __shfl_xor(ssq,1); ssq += __shfl_xor(ssq,2);   // head = 32 cols = 4 lanes
    float inv = 1.f / fmaxf(sqrtf(ssq), 1e-6f);
#pragma unroll
    for (int j = 0; j < 8; ++j) sA[r][c0+j] = acc[j]*inv;
  }
  // k = h1 @ w_k ; normalize -> kn in sB
  {
    float acc[8] = {0,0,0,0,0,0,0,0};
    mm16x128(sH1, w_k, sW, acc, r, c0, tid);
    float ssq = 0.f;
#pragma unroll
    for (int j = 0; j < 8; ++j) ssq += acc[j]*acc[j];
    ssq += __shfl_xor(ssq,1); ssq += __shfl_xor(ssq,2);
    float inv = 1.f / fmaxf(sqrtf(ssq), 1e-6f);
#pragma unroll
    for (int j = 0; j < 8; ++j) sB[r][c0+j] = acc[j]*inv;
  }
  __syncthreads();

  // logits + softmax: wave = head; lane -> (n = lane>>2, 4 m's)
  {
    int hd   = tid >> 6;
    int lane = tid & 63;
    int n    = lane >> 2;
    int mb   = (lane & 3) << 2;
    float scale = expf(fminf(logit_scale[hd], LN100F));
    float l4[4];
#pragma unroll
    for (int mi = 0; mi < 4; ++mi) {
      float s = 0.f;
#pragma unroll
      for (int d = 0; d < 32; ++d) s += sA[n][hd*32+d]*sB[mb+mi][hd*32+d];
      l4[mi] = s*scale;
    }
    float mx = fmaxf(fmaxf(l4[0],l4[1]), fmaxf(l4[2],l4[3]));
    mx = fmaxf(mx, __shfl_xor(mx,1)); mx = fmaxf(mx, __shfl_xor(mx,2));
    float e4[4], sm = 0.f;
#pragma unroll
    for (int mi = 0; mi < 4; ++mi) { e4[mi] = expf(l4[mi]-mx); sm += e4[mi]; }
    sm += __shfl_xor(sm,1); sm += __shfl_xor(sm,2);
    float isv = 1.f/sm;
#pragma unroll
    for (int mi = 0; mi < 4; ++mi) sAttn[hd][n][mb+mi] = e4[mi]*isv;
  }
  __syncthreads();

  // att_out = attn @ v -> sA (qn dead)
  {
    int hd = cg >> 2;
    float acc[8] = {0,0,0,0,0,0,0,0};
#pragma unroll
    for (int m = 0; m < 16; ++m) {
      float a = sAttn[hd][r][m];
#pragma unroll
      for (int j = 0; j < 8; ++j) acc[j] = fmaf(a, sV[m][c0+j], acc[j]);
    }
#pragma unroll
    for (int j = 0; j < 8; ++j) sA[r][c0+j] = acc[j];
  }

  // o-proj + residual + LN2 -> h2 in sB (kn dead)
  {
    float acc[8];
#pragma unroll
    for (int j = 0; j < 8; ++j) acc[j] = b_o[c0+j];
    mm16x128(sA, w_o, sW, acc, r, c0, tid);
    float s2[8], sum = 0.f, ssq = 0.f;
#pragma unroll
    for (int j = 0; j < 8; ++j) { s2[j] = sH1[r][c0+j] + acc[j]; sum += s2[j]; ssq += s2[j]*s2[j]; }
    sum = rowsum16(sum); ssq = rowsum16(ssq);
    float mean = sum * (1.f/128.f);
    float var  = ssq * (1.f/128.f) - mean*mean;
    float rstd = rsqrtf(var + 1e-5f);
#pragma unroll
    for (int j = 0; j < 8; ++j)
      sB[r][c0+j] = (s2[j]-mean)*rstd*ln2_g[c0+j] + ln2_b[c0+j];
  }

  // mlp_nh: a1 = leaky(h2 @ nh_w1 + b1); m = leaky(a1 @ nh_w2 + b2); h3 = h2 + m
  float h3[8]; float msum, mean3, rstd3;
  {
    float acc[32];
#pragma unroll
    for (int f = 0; f < 32; ++f) acc[f] = nh_b1[cg*32+f];
    for (int kc = 0; kc < 8; ++kc) {
      __syncthreads();
      const float4* wg = (const float4*)(nh_w1 + kc*16*512);
      float4* sw4 = (float4*)sW;
#pragma unroll
      for (int i = 0; i < 8; ++i) sw4[tid + i*256] = wg[tid + i*256];
      __syncthreads();
#pragma unroll
      for (int kk = 0; kk < 16; ++kk) {
        float a = sB[r][kc*16+kk];
        const float* wr_ = &sW[kk*512 + cg*32];
#pragma unroll
        for (int f = 0; f < 32; ++f) acc[f] = fmaf(a, wr_[f], acc[f]);
      }
    }
    __syncthreads();
    float pm = 0.f;
#pragma unroll
    for (int f = 0; f < 32; ++f) pm += leakyf(acc[f]) * nh_w2[cg*32+f];
    pm = rowsum16(pm);
    float mval = leakyf(pm + nh_b2[0]);
    float sum = 0.f, ssq = 0.f;
#pragma unroll
    for (int j = 0; j < 8; ++j) { h3[j] = sB[r][c0+j] + mval; sum += h3[j]; ssq += h3[j]*h3[j]; }
    // LN3 over all 2048 elements of this token
    float s = sum, q2 = ssq;
#pragma unroll
    for (int sft = 1; sft < 64; sft <<= 1) { s += __shfl_xor(s,sft); q2 += __shfl_xor(q2,sft); }
    int wv = tid >> 6, lane = tid & 63;
    if (lane == 0) { sRed[wv] = s; sRed[4+wv] = q2; }
    __syncthreads();
    if (tid == 0) {
      float S = sRed[0]+sRed[1]+sRed[2]+sRed[3];
      float Q = sRed[4]+sRed[5]+sRed[6]+sRed[7];
      float mn = S*(1.f/2048.f);
      float vr = Q*(1.f/2048.f) - mn*mn;
      sStats[0] = mn; sStats[1] = rsqrtf(vr + 1e-5f);
    }
    __syncthreads();
    mean3 = sStats[0]; rstd3 = sStats[1]; msum = mval; (void)msum;
  }
  {
    int base = r*128 + c0;
    union { short h[8]; uint4 u; } pk;
#pragma unroll
    for (int j = 0; j < 8; ++j) {
      float y = (h3[j]-mean3)*rstd3*ln3_g[base+j] + ln3_b[base+j];
      pk.h[j] = f2bf(y);
    }
    *(uint4*)(Hn + (size_t)token*MDNH + base) = pk.u;
  }
}

// ---------------------------------------------------------------------------
// K3: bf16 MFMA GEMM, C = leaky(A @ Bt^T + bias). A [M][K], Bt [N][K] (both bf16),
// 128x128 tile, BK=32, 4 waves (2x2), each wave 64x64 via 4x4 16x16x32 frags.
// ---------------------------------------------------------------------------
template<int OUT_BF16>
__global__ __launch_bounds__(256) void gemm_bias_leaky(
    const short* __restrict__ A, const short* __restrict__ Bt,
    const float* __restrict__ bias, void* __restrict__ Cout,
    int M, int N, int K) {
  __shared__ short sA[128*32];
  __shared__ short sB[128*32];
  int mt = M >> 7;
  int bm = blockIdx.x % mt, bn = blockIdx.x / mt;
  int brow = bm << 7, bcol = bn << 7;
  int tid  = threadIdx.x;
  int wid  = tid >> 6, lane = tid & 63;
  int wr = wid >> 1, wc = wid & 1;

  f32x4 acc[4][4];
#pragma unroll
  for (int m = 0; m < 4; ++m)
#pragma unroll
    for (int n = 0; n < 4; ++n) { acc[m][n][0]=0.f; acc[m][n][1]=0.f; acc[m][n][2]=0.f; acc[m][n][3]=0.f; }

  const short* Ab = A  + (size_t)brow*K;
  const short* Bb = Bt + (size_t)bcol*K;
  int ca = wid*128 + lane;        // chunk ids: ca, ca+64 (16B chunks; row=c>>2, seg=c&3)
  int rA0 = ca >> 2,  sA0 = ca & 3;
  int rA1 = (ca+64) >> 2, sA1 = (ca+64) & 3;

  for (int k0 = 0; k0 < K; k0 += 32) {
    uint4 a0 = *(const uint4*)(Ab + (size_t)rA0*K + k0 + sA0*8);
    uint4 a1 = *(const uint4*)(Ab + (size_t)rA1*K + k0 + sA1*8);
    uint4 b0 = *(const uint4*)(Bb + (size_t)rA0*K + k0 + sA0*8);
    uint4 b1 = *(const uint4*)(Bb + (size_t)rA1*K + k0 + sA1*8);
    __syncthreads();
    *(uint4*)&sA[(size_t)ca*8]      = a0;
    *(uint4*)&sA[(size_t)(ca+64)*8] = a1;
    *(uint4*)&sB[(size_t)ca*8]      = b0;
    *(uint4*)&sB[(size_t)(ca+64)*8] = b1;
    __syncthreads();
    bf16x8 af[4], bfr[4];
#pragma unroll
    for (int m = 0; m < 4; ++m) af[m]  = *(bf16x8*)&sA[(wr*64 + m*16 + (lane&15))*32 + (lane>>4)*8];
#pragma unroll
    for (int n = 0; n < 4; ++n) bfr[n] = *(bf16x8*)&sB[(wc*64 + n*16 + (lane&15))*32 + (lane>>4)*8];
#pragma unroll
    for (int m = 0; m < 4; ++m)
#pragma unroll
      for (int n = 0; n < 4; ++n)
        acc[m][n] = __builtin_amdgcn_mfma_f32_16x16x32_bf16(af[m], bfr[n], acc[m][n], 0, 0, 0);
  }

  int lr = (lane >> 4) * 4, lc = lane & 15;
#pragma unroll
  for (int n = 0; n < 4; ++n) {
    int col = bcol + wc*64 + n*16 + lc;
    float bv = bias[col];
#pragma unroll
    for (int m = 0; m < 4; ++m) {
      int row0 = brow + wr*64 + m*16 + lr;
#pragma unroll
      for (int i = 0; i < 4; ++i) {
        float v = leakyf(acc[m][n][i] + bv);
        if (OUT_BF16) ((short*)Cout)[(size_t)(row0+i)*N + col] = f2bf(v);
        else          ((float*)Cout)[(size_t)(row0+i)*N + col] = v;
      }
    }
  }
}

// ---------------------------------------------------------------------------
extern "C" void kernel_launch(void* const* d_in, const int* in_sizes, int n_in,
                              void* d_out, int out_size, void* d_ws, size_t ws_size,
                              hipStream_t stream) {
  const float* x      = (const float*)d_in[0];
  const float* coords = (const float*)d_in[1];
  const float* w_v    = (const float*)d_in[2];
  const float* w_q    = (const float*)d_in[3];
  const float* w_k    = (const float*)d_in[4];
  const float* pe_w1  = (const float*)d_in[5];
  const float* pe_b1  = (const float*)d_in[6];
  const float* pe_w2  = (const float*)d_in[7];
  const float* pe_b2  = (const float*)d_in[8];
  const float* lscale = (const float*)d_in[9];
  const float* w_o    = (const float*)d_in[10];
  const float* b_o    = (const float*)d_in[11];
  const float* nh_w1  = (const float*)d_in[12];
  const float* nh_b1  = (const float*)d_in[13];
  const float* nh_w2  = (const float*)d_in[14];
  const float* nh_b2  = (const float*)d_in[15];
  const float* u_w1   = (const float*)d_in[16];
  const float* u_b1   = (const float*)d_in[17];
  const float* u_w2   = (const float*)d_in[18];
  const float* u_b2   = (const float*)d_in[19];
  const float* ln1_g  = (const float*)d_in[20];
  const float* ln1_b  = (const float*)d_in[21];
  const float* ln2_g  = (const float*)d_in[22];
  const float* ln2_b  = (const float*)d_in[23];
  const float* ln3_g  = (const float*)d_in[24];
  const float* ln3_b  = (const float*)d_in[25];

  char* ws = (char*)d_ws;
  int*   idxb = (int*)ws;                           // 1 MB
  float* csb  = (float*)(ws + (1ull<<20));          // 2 MB
  short* w1t  = (short*)(ws + (4ull<<20));          // 8 MB
  short* w2t  = (short*)(ws + (12ull<<20));         // 8 MB
  short* G1   = (short*)(ws + (20ull<<20));         // 64 MB
  // Hn (bf16, 64MB) lives in d_out's space: fully consumed by GEMM1 before
  // GEMM2 overwrites d_out (stream-ordered).
  short* Hn   = (short*)d_out;

  dim3 tgrid(MDNH/32, MDNH/32);
  transpose_to_bf16<<<tgrid, 256, 0, stream>>>(u_w1, w1t, MDNH, MDNH);
  transpose_to_bf16<<<tgrid, 256, 0, stream>>>(u_w2, w2t, MDNH, MDNH);

  knn_kernel<<<BT/4, 256, 0, stream>>>(coords, idxb, csb);

  token_kernel<<<BT, 256, 0, stream>>>(x, idxb, csb, w_v, w_q, w_k,
      pe_w1, pe_b1, pe_w2, pe_b2, lscale, w_o, b_o,
      nh_w1, nh_b1, nh_w2, nh_b2,
      ln1_g, ln1_b, ln2_g, ln2_b, ln3_g, ln3_b, Hn);

  int mt = BT/128, nt = MDNH/128;
  gemm_bias_leaky<1><<<mt*nt, 256, 0, stream>>>(Hn, w1t, u_b1, G1, BT, MDNH, MDNH);
  gemm_bias_leaky<0><<<mt*nt, 256, 0, stream>>>(G1, w2t, u_b2, (float*)d_out, BT, MDNH, MDNH);
}

// Round 6
// 1215.394 us; speedup vs baseline: 5.0245x; 5.0245x over previous
//
#include <hip/hip_runtime.h>
#include <hip/hip_bf16.h>
#include <stdint.h>

#define TLEN   4096
#define BATCH  4
#define BT     (BATCH*TLEN)
#define MDNH   2048
#define LN100F 4.605170185988092f

typedef __attribute__((ext_vector_type(8))) short bf16x8;
typedef __attribute__((ext_vector_type(4))) float f32x4;
typedef unsigned int u32;

__device__ __forceinline__ float leakyf(float v){ return v >= 0.f ? v : 0.2f*v; }
__device__ __forceinline__ short f2bf(float v){ __hip_bfloat16 h = __float2bfloat16(v); return *reinterpret_cast<short*>(&h); }
__device__ __forceinline__ float bf2f(short s){
  union { u32 u; float f; } cv; cv.u = ((u32)(unsigned short)s) << 16; return cv.f;
}
// swizzled element offset for [128][128] bf16 LDS tiles (row stride 256B)
__device__ __forceinline__ int sw128(int row, int col){ return row*128 + (col ^ ((row&7)<<3)); }
// sum across the 16 lanes differing in bits 0..3 (the C-frag column direction)
__device__ __forceinline__ float redcol(float v){
  v += __shfl_xor(v,1); v += __shfl_xor(v,2); v += __shfl_xor(v,4); v += __shfl_xor(v,8);
  return v;
}

// ---------------------------------------------------------------------------
// K1: exact KNN (top-16 by squared Euclidean distance, ties -> lower index).
// ---------------------------------------------------------------------------
__global__ __launch_bounds__(256) void knn_kernel(const float* __restrict__ coords,
                                                  int* __restrict__ idx_out,
                                                  float* __restrict__ cs_out) {
  __shared__ float sc[TLEN*2];
  int blk = blockIdx.x;
  int bb  = blk >> 10;
  int q0  = (blk & 1023) << 2;
  const float4* cb4 = (const float4*)(coords + (size_t)bb*TLEN*2);
  for (int i = threadIdx.x; i < TLEN*2/4; i += 256) ((float4*)sc)[i] = cb4[i];
  __syncthreads();

  int wid  = threadIdx.x >> 6;
  int lane = threadIdx.x & 63;
  int q    = q0 + wid;
  float qx = sc[q*2], qy = sc[q*2+1];

  unsigned long long top[16];
#pragma unroll
  for (int j = 0; j < 16; ++j) top[j] = ~0ull;

  for (int c = lane; c < TLEN; c += 64) {
    float dx = __fsub_rn(sc[c*2],   qx);
    float dy = __fsub_rn(sc[c*2+1], qy);
    float d2 = __fadd_rn(__fmul_rn(dx,dx), __fmul_rn(dy,dy));
    unsigned long long key = ((unsigned long long)__float_as_uint(d2) << 32) | (unsigned)c;
    if (key < top[15]) {
#pragma unroll
      for (int j = 15; j >= 1; --j)
        top[j] = (key < top[j-1]) ? top[j-1] : ((key < top[j]) ? key : top[j]);
      top[0] = (key < top[0]) ? key : top[0];
    }
  }

  unsigned long long myres = 0;
  for (int k = 0; k < 16; ++k) {
    unsigned long long m = top[0];
#pragma unroll
    for (int s = 1; s < 64; s <<= 1) {
      unsigned long long o = __shfl_xor(m, s);
      m = (o < m) ? o : m;
    }
    if (lane == k) myres = m;
    if (top[0] == m) {
#pragma unroll
      for (int j = 0; j < 15; ++j) top[j] = top[j+1];
      top[15] = ~0ull;
    }
  }
  if (lane < 16) {
    int ci = (int)(unsigned)(myres & 0xffffffffull);
    size_t o = ((size_t)(bb*TLEN + q))*16 + lane;
    idx_out[o] = ci;
    cs_out[o*2+0] = __fsub_rn(sc[ci*2],   qx);
    cs_out[o*2+1] = __fsub_rn(sc[ci*2+1], qy);
  }
}

// ---------------------------------------------------------------------------
// K0: fp32 [R][C] -> bf16 transposed [C][R]
// ---------------------------------------------------------------------------
__global__ __launch_bounds__(256) void transpose_to_bf16(const float* __restrict__ in,
                                                         short* __restrict__ out,
                                                         int R, int C) {
  __shared__ float tile[32][33];
  int c0 = blockIdx.x*32, r0 = blockIdx.y*32;
  int tx = threadIdx.x & 31, ty = threadIdx.x >> 5;
  for (int i = ty; i < 32; i += 8) tile[i][tx] = in[(size_t)(r0+i)*C + c0+tx];
  __syncthreads();
  for (int i = ty; i < 32; i += 8) out[(size_t)(c0+i)*R + r0+tx] = f2bf(tile[tx][i]);
}

// ---------------------------------------------------------------------------
// per-wave [16 rows] x [128 out] x K=128 MFMA GEMM.
// ---------------------------------------------------------------------------
__device__ __forceinline__ void gemm128(const short* Asrc, short* sW,
                                        const short* __restrict__ Wt,
                                        f32x4 acc[8], int w, int lane, int tid) {
#pragma unroll
  for (int ph = 0; ph < 2; ++ph) {
    __syncthreads();                      // protect previous sW readers
#pragma unroll
    for (int q = 0; q < 2; ++q) {
      int c = tid + 512*q;                // 0..1023 chunks of 16B
      int row = c >> 3, slot = c & 7;     // 8 slots x 16B = 128B rows
      uint4 wv = *(const uint4*)(Wt + (size_t)row*128 + ph*64 + slot*8);
      *(uint4*)&sW[row*64 + ((slot*8) ^ ((row&7)<<3))] = wv;
    }
    __syncthreads();
#pragma unroll
    for (int ks = 0; ks < 2; ++ks) {
      bf16x8 af = *(const bf16x8*)&Asrc[sw128(16*w + (lane&15),
                                              ph*64 + ks*32 + (lane>>4)*8)];
#pragma unroll
      for (int nf = 0; nf < 8; ++nf) {
        int wr = nf*16 + (lane&15);
        bf16x8 bv = *(const bf16x8*)&sW[wr*64 + ((ks*32 + (lane>>4)*8) ^ ((wr&7)<<3))];
        acc[nf] = __builtin_amdgcn_mfma_f32_16x16x32_bf16(af, bv, acc[nf], 0, 0, 0);
      }
    }
  }
}

__device__ __forceinline__ void frag_store(short* buf, const f32x4* acc, int w, int lane) {
  int rb = 16*w + (lane>>4)*4;
  int cc = lane & 15;
#pragma unroll
  for (int nf = 0; nf < 8; ++nf)
#pragma unroll
    for (int i = 0; i < 4; ++i)
      buf[sw128(rb+i, nf*16+cc)] = f2bf(acc[nf][i]);
}

// ---------------------------------------------------------------------------
// K2: fused per-token pipeline. 8 tokens/block, 512 threads, wave = token.
// This round: attention is VALU (bisect the round-5 correctness failure).
// ---------------------------------------------------------------------------
__global__ __launch_bounds__(512) void token_mfma(
    const float* __restrict__ x, const int* __restrict__ idx, const float* __restrict__ cs,
    const short* __restrict__ wvt, const short* __restrict__ wqt, const short* __restrict__ wkt,
    const short* __restrict__ wot, const short* __restrict__ pew2t, const short* __restrict__ nhw1t,
    const float* __restrict__ pe_w1, const float* __restrict__ pe_b1, const float* __restrict__ pe_b2,
    const float* __restrict__ lscale, const float* __restrict__ b_o,
    const float* __restrict__ nh_b1, const float* __restrict__ nh_w2, const float* __restrict__ nh_b2,
    const float* __restrict__ ln1_g, const float* __restrict__ ln1_b,
    const float* __restrict__ ln2_g, const float* __restrict__ ln2_b,
    const float* __restrict__ ln3_g, const float* __restrict__ ln3_b,
    short* __restrict__ Hn) {
  __shared__ short sA[128*128];   // xg -> qn -> att -> h2       (32KB)
  __shared__ short sB[128*128];   // hid -> kn -> P(f32) -> h3n  (32KB)
  __shared__ short sH[128*128];   // h1 (A for q/k)              (32KB)
  __shared__ short sV[128*128];   // v                           (32KB)
  __shared__ short sW[128*64];    // weight phase stage          (16KB)

  const int tid  = threadIdx.x;
  const int w    = tid >> 6;
  const int lane = tid & 63;
  const int cc   = lane & 15;
  const int kg   = lane >> 4;           // 0..3
  const int r0   = 16*w + kg*4;         // C-frag row base
  const int token = blockIdx.x*8 + w;
  const int batch = token >> 12;

  // --- per-token idx/cs preload (lanes 0..15) ---
  int myidx = 0; float mcsx = 0.f, mcsy = 0.f;
  if (lane < 16) {
    size_t o = (size_t)token*16 + lane;
    myidx = idx[o];
    mcsx  = cs[o*2];
    mcsy  = cs[o*2+1];
  }

  // --- gather xg -> sA, pe-hidden -> sB (wave-local rows) ---
#pragma unroll
  for (int p = 0; p < 4; ++p) {
    int c   = lane + 64*p;      // 0..255
    int rl  = c >> 4;           // row within token
    int seg = c & 15;           // 8-elem segment
    int xr  = __shfl(myidx, rl);
    const float* gp = x + ((size_t)batch*TLEN + xr)*128 + seg*8;
    float4 a = *(const float4*)gp;
    float4 b = *(const float4*)(gp+4);
    union { short h[8]; uint4 u; } pk;
    pk.h[0]=f2bf(a.x); pk.h[1]=f2bf(a.y); pk.h[2]=f2bf(a.z); pk.h[3]=f2bf(a.w);
    pk.h[4]=f2bf(b.x); pk.h[5]=f2bf(b.y); pk.h[6]=f2bf(b.z); pk.h[7]=f2bf(b.w);
    *(uint4*)&sA[sw128(16*w+rl, seg*8)] = pk.u;

    float cx = __shfl(mcsx, rl), cy = __shfl(mcsy, rl);
    int col0 = seg*8;
    float pw0[8], pw1[8], pb1[8];
    *(float4*)&pw0[0] = *(const float4*)(pe_w1 + col0);
    *(float4*)&pw0[4] = *(const float4*)(pe_w1 + col0 + 4);
    *(float4*)&pw1[0] = *(const float4*)(pe_w1 + 128 + col0);
    *(float4*)&pw1[4] = *(const float4*)(pe_w1 + 128 + col0 + 4);
    *(float4*)&pb1[0] = *(const float4*)(pe_b1 + col0);
    *(float4*)&pb1[4] = *(const float4*)(pe_b1 + col0 + 4);
    union { short h[8]; uint4 u; } pk2;
#pragma unroll
    for (int j = 0; j < 8; ++j) pk2.h[j] = f2bf(leakyf(cx*pw0[j] + cy*pw1[j] + pb1[j]));
    *(uint4*)&sB[sw128(16*w+rl, seg*8)] = pk2.u;
  }

  f32x4 acc[8];
  f32x4 h1v[8];   // fp32 residual state (h1, later h2)

  // ---- pe GEMM: pe = hid @ pe_w2 + b2; s1 = xg + pe; LN1 -> h1 ----
#pragma unroll
  for (int nf = 0; nf < 8; ++nf) { float b = pe_b2[nf*16+cc]; acc[nf] = (f32x4){b,b,b,b}; }
  gemm128(sB, sW, pew2t, acc, w, lane, tid);
  {
#pragma unroll
    for (int nf = 0; nf < 8; ++nf)
#pragma unroll
      for (int i = 0; i < 4; ++i)
        acc[nf][i] += bf2f(sA[sw128(r0+i, nf*16+cc)]);
    float sum[4] = {0,0,0,0}, ssq[4] = {0,0,0,0};
#pragma unroll
    for (int nf = 0; nf < 8; ++nf)
#pragma unroll
      for (int i = 0; i < 4; ++i) { float v = acc[nf][i]; sum[i] += v; ssq[i] += v*v; }
    float rstd[4], mean[4];
#pragma unroll
    for (int i = 0; i < 4; ++i) {
      float s = redcol(sum[i]), q2 = redcol(ssq[i]);
      mean[i] = s*(1.f/128.f);
      rstd[i] = rsqrtf(q2*(1.f/128.f) - mean[i]*mean[i] + 1e-5f);
    }
#pragma unroll
    for (int nf = 0; nf < 8; ++nf) {
      float g = ln1_g[nf*16+cc], b = ln1_b[nf*16+cc];
#pragma unroll
      for (int i = 0; i < 4; ++i) h1v[nf][i] = (acc[nf][i]-mean[i])*rstd[i]*g + b;
    }
  }
  frag_store(sH, h1v, w, lane);

  // ---- v = xg @ w_v ----
#pragma unroll
  for (int nf = 0; nf < 8; ++nf) acc[nf] = (f32x4){0,0,0,0};
  gemm128(sA, sW, wvt, acc, w, lane, tid);
  frag_store(sV, acc, w, lane);

  // ---- q = h1 @ w_q ; per-head L2 normalize -> qn in sA ----
#pragma unroll
  for (int nf = 0; nf < 8; ++nf) acc[nf] = (f32x4){0,0,0,0};
  gemm128(sH, sW, wqt, acc, w, lane, tid);
#pragma unroll
  for (int h = 0; h < 4; ++h)
#pragma unroll
    for (int i = 0; i < 4; ++i) {
      float ss = acc[2*h][i]*acc[2*h][i] + acc[2*h+1][i]*acc[2*h+1][i];
      ss = redcol(ss);
      float inv = 1.f / fmaxf(sqrtf(ss), 1e-6f);
      acc[2*h][i] *= inv; acc[2*h+1][i] *= inv;
    }
  frag_store(sA, acc, w, lane);

  // ---- k = h1 @ w_k ; normalize -> kn in sB ----
#pragma unroll
  for (int nf = 0; nf < 8; ++nf) acc[nf] = (f32x4){0,0,0,0};
  gemm128(sH, sW, wkt, acc, w, lane, tid);
#pragma unroll
  for (int h = 0; h < 4; ++h)
#pragma unroll
    for (int i = 0; i < 4; ++i) {
      float ss = acc[2*h][i]*acc[2*h][i] + acc[2*h+1][i]*acc[2*h+1][i];
      ss = redcol(ss);
      float inv = 1.f / fmaxf(sqrtf(ss), 1e-6f);
      acc[2*h][i] *= inv; acc[2*h+1][i] *= inv;
    }
  frag_store(sB, acc, w, lane);

  // ---- attention (VALU, wave-local; P kept fp32 in sB's storage) ----
  {
    float* sPf = (float*)sB;   // [128 rows][64 floats]; kn dead after logits
    float scl[4];
#pragma unroll
    for (int h = 0; h < 4; ++h) scl[h] = expf(fminf(lscale[h], LN100F));

    // logits: lane (kg,cc): q = cc, k = kg*4+kk
    float lgt[4][4];           // [h][kk]
#pragma unroll
    for (int h = 0; h < 4; ++h) {
      bf16x8 qv[4];
#pragma unroll
      for (int s = 0; s < 4; ++s)
        qv[s] = *(const bf16x8*)&sA[sw128(16*w + cc, h*32 + s*8)];
#pragma unroll
      for (int kk = 0; kk < 4; ++kk) {
        int k = kg*4 + kk;
        float d = 0.f;
#pragma unroll
        for (int s = 0; s < 4; ++s) {
          bf16x8 kv = *(const bf16x8*)&sB[sw128(16*w + k, h*32 + s*8)];
#pragma unroll
          for (int j = 0; j < 8; ++j) d += bf2f(qv[s][j]) * bf2f(kv[j]);
        }
        lgt[h][kk] = d * scl[h];
      }
    }
    // softmax over k (4 local regs x kg via shfl bits 4,5); write fp32 P
#pragma unroll
    for (int h = 0; h < 4; ++h) {
      float m = fmaxf(fmaxf(lgt[h][0],lgt[h][1]), fmaxf(lgt[h][2],lgt[h][3]));
      m = fmaxf(m, __shfl_xor(m,16)); m = fmaxf(m, __shfl_xor(m,32));
      float e[4], s_ = 0.f;
#pragma unroll
      for (int kk = 0; kk < 4; ++kk) { e[kk] = expf(lgt[h][kk]-m); s_ += e[kk]; }
      s_ += __shfl_xor(s_,16); s_ += __shfl_xor(s_,32);
      float inv = 1.f/s_;
#pragma unroll
      for (int kk = 0; kk < 4; ++kk)
        sPf[(16*w + cc)*64 + h*16 + kg*4 + kk] = e[kk]*inv;
    }
    // PV: acc over k; lane (kg,cc): rows kg*4+i, cols nf*16+cc
    f32x4 av[8];
#pragma unroll
    for (int nf = 0; nf < 8; ++nf) av[nf] = (f32x4){0,0,0,0};
    for (int k = 0; k < 16; ++k) {
      float pv4[4][4];  // [h][i]
#pragma unroll
      for (int i = 0; i < 4; ++i)
#pragma unroll
        for (int h = 0; h < 4; ++h)
          pv4[h][i] = sPf[(16*w + kg*4 + i)*64 + h*16 + k];
#pragma unroll
      for (int nf = 0; nf < 8; ++nf) {
        float vv = bf2f(sV[sw128(16*w + k, nf*16 + cc)]);
        int h = nf >> 1;
#pragma unroll
        for (int i = 0; i < 4; ++i) av[nf][i] += pv4[h][i] * vv;
      }
    }
    frag_store(sA, av, w, lane);   // att -> sA (qn dead)
  }

  // ---- o-proj + residual + LN2 -> h2 ----
#pragma unroll
  for (int nf = 0; nf < 8; ++nf) { float b = b_o[nf*16+cc]; acc[nf] = (f32x4){b,b,b,b}; }
  gemm128(sA, sW, wot, acc, w, lane, tid);
  {
#pragma unroll
    for (int nf = 0; nf < 8; ++nf)
#pragma unroll
      for (int i = 0; i < 4; ++i) acc[nf][i] += h1v[nf][i];
    float sum[4] = {0,0,0,0}, ssq[4] = {0,0,0,0};
#pragma unroll
    for (int nf = 0; nf < 8; ++nf)
#pragma unroll
      for (int i = 0; i < 4; ++i) { float v = acc[nf][i]; sum[i] += v; ssq[i] += v*v; }
    float rstd[4], mean[4];
#pragma unroll
    for (int i = 0; i < 4; ++i) {
      float s = redcol(sum[i]), q2 = redcol(ssq[i]);
      mean[i] = s*(1.f/128.f);
      rstd[i] = rsqrtf(q2*(1.f/128.f) - mean[i]*mean[i] + 1e-5f);
    }
#pragma unroll
    for (int nf = 0; nf < 8; ++nf) {
      float g = ln2_g[nf*16+cc], b = ln2_b[nf*16+cc];
#pragma unroll
      for (int i = 0; i < 4; ++i) h1v[nf][i] = (acc[nf][i]-mean[i])*rstd[i]*g + b; // now h2
    }
  }
  frag_store(sA, h1v, w, lane);    // h2 -> sA (A for nh GEMM)

  // ---- mlp_nh: m = leaky(leaky(h2@W1+b1)@W2+b2); h3 = h2+m; LN3 ----
  float pm[4] = {0,0,0,0};
#pragma unroll
  for (int chn = 0; chn < 4; ++chn) {
#pragma unroll
    for (int nf = 0; nf < 8; ++nf) { float b = nh_b1[chn*128 + nf*16+cc]; acc[nf] = (f32x4){b,b,b,b}; }
    gemm128(sA, sW, nhw1t + (size_t)chn*128*128, acc, w, lane, tid);
#pragma unroll
    for (int nf = 0; nf < 8; ++nf) {
      float w2v = nh_w2[chn*128 + nf*16 + cc];
#pragma unroll
      for (int i = 0; i < 4; ++i) pm[i] += leakyf(acc[nf][i]) * w2v;
    }
  }
  {
    float b2 = nh_b2[0];
    float mval[4];
#pragma unroll
    for (int i = 0; i < 4; ++i) mval[i] = leakyf(redcol(pm[i]) + b2);
    float tsum = 0.f, tssq = 0.f;
#pragma unroll
    for (int nf = 0; nf < 8; ++nf)
#pragma unroll
      for (int i = 0; i < 4; ++i) {
        float h3 = h1v[nf][i] + mval[i];
        acc[nf][i] = h3;
        tsum += h3; tssq += h3*h3;
      }
#pragma unroll
    for (int s = 1; s < 64; s <<= 1) { tsum += __shfl_xor(tsum,s); tssq += __shfl_xor(tssq,s); }
    float mean = tsum*(1.f/2048.f);
    float rstd = rsqrtf(tssq*(1.f/2048.f) - mean*mean + 1e-5f);
#pragma unroll
    for (int nf = 0; nf < 8; ++nf)
#pragma unroll
      for (int i = 0; i < 4; ++i) acc[nf][i] = (acc[nf][i]-mean)*rstd;
  }
  frag_store(sB, acc, w, lane);    // normalized h3 (pre-gain) -> sB

  // ---- apply ln3 g/b and write Hn coalesced ----
#pragma unroll
  for (int p = 0; p < 4; ++p) {
    int c   = lane + 64*p;
    int rl  = c >> 4;
    int seg = c & 15;
    bf16x8 hv = *(const bf16x8*)&sB[sw128(16*w+rl, seg*8)];
    float gv[8], bv[8];
    *(float4*)&gv[0] = *(const float4*)(ln3_g + rl*128 + seg*8);
    *(float4*)&gv[4] = *(const float4*)(ln3_g + rl*128 + seg*8 + 4);
    *(float4*)&bv[0] = *(const float4*)(ln3_b + rl*128 + seg*8);
    *(float4*)&bv[4] = *(const float4*)(ln3_b + rl*128 + seg*8 + 4);
    union { short h[8]; uint4 u; } pk;
#pragma unroll
    for (int j = 0; j < 8; ++j) pk.h[j] = f2bf(bf2f(hv[j])*gv[j] + bv[j]);
    *(uint4*)(Hn + (size_t)token*MDNH + rl*128 + seg*8) = pk.u;
  }
}

// ---------------------------------------------------------------------------
// K3: bf16 MFMA GEMM, C = leaky(A @ Bt^T + bias)  [round-1 validated version]
// ---------------------------------------------------------------------------
template<int OUT_BF16>
__global__ __launch_bounds__(256) void gemm_bias_leaky(
    const short* __restrict__ A, const short* __restrict__ Bt,
    const float* __restrict__ bias, void* __restrict__ Cout,
    int M, int N, int K) {
  __shared__ short sA[128*32];
  __shared__ short sB[128*32];
  int mt = M >> 7;
  int bm = blockIdx.x % mt, bn = blockIdx.x / mt;
  int brow = bm << 7, bcol = bn << 7;
  int tid  = threadIdx.x;
  int wid  = tid >> 6, lane = tid & 63;
  int wr = wid >> 1, wc = wid & 1;

  f32x4 acc[4][4];
#pragma unroll
  for (int m = 0; m < 4; ++m)
#pragma unroll
    for (int n = 0; n < 4; ++n) { acc[m][n][0]=0.f; acc[m][n][1]=0.f; acc[m][n][2]=0.f; acc[m][n][3]=0.f; }

  const short* Ab = A  + (size_t)brow*K;
  const short* Bb = Bt + (size_t)bcol*K;
  int ca = wid*128 + lane;        // chunk ids: ca, ca+64 (16B chunks; row=c>>2, seg=c&3)
  int rA0 = ca >> 2,  sA0 = ca & 3;
  int rA1 = (ca+64) >> 2, sA1 = (ca+64) & 3;

  for (int k0 = 0; k0 < K; k0 += 32) {
    uint4 a0 = *(const uint4*)(Ab + (size_t)rA0*K + k0 + sA0*8);
    uint4 a1 = *(const uint4*)(Ab + (size_t)rA1*K + k0 + sA1*8);
    uint4 b0 = *(const uint4*)(Bb + (size_t)rA0*K + k0 + sA0*8);
    uint4 b1 = *(const uint4*)(Bb + (size_t)rA1*K + k0 + sA1*8);
    __syncthreads();
    *(uint4*)&sA[(size_t)ca*8]      = a0;
    *(uint4*)&sA[(size_t)(ca+64)*8] = a1;
    *(uint4*)&sB[(size_t)ca*8]      = b0;
    *(uint4*)&sB[(size_t)(ca+64)*8] = b1;
    __syncthreads();
    bf16x8 af[4], bfr[4];
#pragma unroll
    for (int m = 0; m < 4; ++m) af[m]  = *(bf16x8*)&sA[(wr*64 + m*16 + (lane&15))*32 + (lane>>4)*8];
#pragma unroll
    for (int n = 0; n < 4; ++n) bfr[n] = *(bf16x8*)&sB[(wc*64 + n*16 + (lane&15))*32 + (lane>>4)*8];
#pragma unroll
    for (int m = 0; m < 4; ++m)
#pragma unroll
      for (int n = 0; n < 4; ++n)
        acc[m][n] = __builtin_amdgcn_mfma_f32_16x16x32_bf16(af[m], bfr[n], acc[m][n], 0, 0, 0);
  }

  int lr = (lane >> 4) * 4, lc = lane & 15;
#pragma unroll
  for (int n = 0; n < 4; ++n) {
    int col = bcol + wc*64 + n*16 + lc;
    float bv = bias[col];
#pragma unroll
    for (int m = 0; m < 4; ++m) {
      int row0 = brow + wr*64 + m*16 + lr;
#pragma unroll
      for (int i = 0; i < 4; ++i) {
        float v = leakyf(acc[m][n][i] + bv);
        if (OUT_BF16) ((short*)Cout)[(size_t)(row0+i)*N + col] = f2bf(v);
        else          ((float*)Cout)[(size_t)(row0+i)*N + col] = v;
      }
    }
  }
}

// ---------------------------------------------------------------------------
extern "C" void kernel_launch(void* const* d_in, const int* in_sizes, int n_in,
                              void* d_out, int out_size, void* d_ws, size_t ws_size,
                              hipStream_t stream) {
  const float* x      = (const float*)d_in[0];
  const float* coords = (const float*)d_in[1];
  const float* w_v    = (const float*)d_in[2];
  const float* w_q    = (const float*)d_in[3];
  const float* w_k    = (const float*)d_in[4];
  const float* pe_w1  = (const float*)d_in[5];
  const float* pe_b1  = (const float*)d_in[6];
  const float* pe_w2  = (const float*)d_in[7];
  const float* pe_b2  = (const float*)d_in[8];
  const float* lscale = (const float*)d_in[9];
  const float* w_o    = (const float*)d_in[10];
  const float* b_o    = (const float*)d_in[11];
  const float* nh_w1  = (const float*)d_in[12];
  const float* nh_b1  = (const float*)d_in[13];
  const float* nh_w2  = (const float*)d_in[14];
  const float* nh_b2  = (const float*)d_in[15];
  const float* u_w1   = (const float*)d_in[16];
  const float* u_b1   = (const float*)d_in[17];
  const float* u_w2   = (const float*)d_in[18];
  const float* u_b2   = (const float*)d_in[19];
  const float* ln1_g  = (const float*)d_in[20];
  const float* ln1_b  = (const float*)d_in[21];
  const float* ln2_g  = (const float*)d_in[22];
  const float* ln2_b  = (const float*)d_in[23];
  const float* ln3_g  = (const float*)d_in[24];
  const float* ln3_b  = (const float*)d_in[25];

  char* ws = (char*)d_ws;
  int*   idxb = (int*)ws;                          // 1 MB @ 0
  float* csb  = (float*)(ws + (1ull<<20));         // 2 MB @ 1MB
  short* wvt  = (short*)(ws + (3ull<<20));                 // 32KB each
  short* wqt  = (short*)(ws + (3ull<<20) + 32*1024);
  short* wkt  = (short*)(ws + (3ull<<20) + 64*1024);
  short* wot  = (short*)(ws + (3ull<<20) + 96*1024);
  short* pew2t= (short*)(ws + (3ull<<20) + 128*1024);
  short* nhw1t= (short*)(ws + (3ull<<20) + 160*1024);      // 128KB
  short* uw1t = (short*)(ws + (4ull<<20));         // 8 MB @ 4MB
  short* uw2t = (short*)(ws + (12ull<<20));        // 8 MB @ 12MB
  short* G1   = (short*)(ws + (20ull<<20));        // 64 MB @ 20MB
  short* Hn   = (short*)d_out;                     // scratch in d_out (consumed before final write)

  dim3 t128(4,4), tnh(16,4), t2k(64,64);
  transpose_to_bf16<<<t128, 256, 0, stream>>>(w_v,   wvt,   128, 128);
  transpose_to_bf16<<<t128, 256, 0, stream>>>(w_q,   wqt,   128, 128);
  transpose_to_bf16<<<t128, 256, 0, stream>>>(w_k,   wkt,   128, 128);
  transpose_to_bf16<<<t128, 256, 0, stream>>>(w_o,   wot,   128, 128);
  transpose_to_bf16<<<t128, 256, 0, stream>>>(pe_w2, pew2t, 128, 128);
  transpose_to_bf16<<<tnh,  256, 0, stream>>>(nh_w1, nhw1t, 128, 512);
  transpose_to_bf16<<<t2k,  256, 0, stream>>>(u_w1,  uw1t,  MDNH, MDNH);
  transpose_to_bf16<<<t2k,  256, 0, stream>>>(u_w2,  uw2t,  MDNH, MDNH);

  knn_kernel<<<BT/4, 256, 0, stream>>>(coords, idxb, csb);

  token_mfma<<<BT/8, 512, 0, stream>>>(x, idxb, csb,
      wvt, wqt, wkt, wot, pew2t, nhw1t,
      pe_w1, pe_b1, pe_b2, lscale, b_o,
      nh_b1, nh_w2, nh_b2,
      ln1_g, ln1_b, ln2_g, ln2_b, ln3_g, ln3_b, Hn);

  int mt = BT/128, nt = MDNH/128;
  gemm_bias_leaky<1><<<mt*nt, 256, 0, stream>>>(Hn, uw1t, u_b1, G1, BT, MDNH, MDNH);
  gemm_bias_leaky<0><<<mt*nt, 256, 0, stream>>>(G1, uw2t, u_b2, (float*)d_out, BT, MDNH, MDNH);
}